// Round 13
// baseline (324.526 us; speedup 1.0000x reference)
//
#include <hip/hip_runtime.h>
#include <hip/hip_fp16.h>

// img [1,1,160,192,224] fp32, phi [1,3,160,192,224] fp32, out img-shaped fp32.
// coord_d = clip((phi_d*2-1+1)*0.5*(sz_d-1), 0, sz_d-1); trilinear, border clamp.
//
// Round 7: sampler is fabric-byte-bound at ~3.8 TB/s (rounds 2/3/6 all pin this).
// fp16 (x2,y4,z4) bricks (round 6, verified) + NEW: 4 slab passes. Pass p
// handles samples with x0 in [40p,40p+40): per-pass gather working set 3.6 MB
// fits a 4 MB per-XCD L2 -> gathers become hits; image fabric traffic drops to
// per-XCD compulsory (~115 MB total). phi re-read per pass is coalesced nt
// streams (cheap bytes); out writes amplify ~4x on partial lines (accepted).

#define DD 160
#define HH 192
#define WW 224
#define NTOT (DD * HH * WW)  // 6,881,280

// Brick grid: line = 64B = 32 fp16 = (x:2, y:4, z:4)
#define XB 80
#define YB 48
#define ZB 56
#define NLINES (XB * YB * ZB)  // 215,040 lines = 13.76 MB

#define NPASS 4
#define SLABX 40  // x-planes per slab (160/4)

// ---------------- repack: img fp32 linear -> fp16 bricked (round-6 verified) --
__global__ __launch_bounds__(256) void vm_repack_kernel(
    const float* __restrict__ img, __half2* __restrict__ bimg) {
  int t = blockIdx.x * 256 + threadIdx.x;
  if (t >= NLINES) return;
  int zb = t % ZB;
  int tmp = t / ZB;
  int yb = tmp % YB;
  int xb = tmp / YB;
  int x0 = xb * 2, y0 = yb * 4, z0 = zb * 4;

  __half2 h2[16];
#pragma unroll
  for (int dx = 0; dx < 2; ++dx) {
#pragma unroll
    for (int dy = 0; dy < 4; ++dy) {
      const float4 v =
          *(const float4*)&img[(((x0 + dx) * HH) + (y0 + dy)) * WW + z0];
      int base = dx * 8 + dy * 2;
      h2[base + 0] = __floats2half2_rn(v.x, v.y);
      h2[base + 1] = __floats2half2_rn(v.z, v.w);
    }
  }
  float4* dst = (float4*)&bimg[t * 16];
  const float4* src = (const float4*)h2;
#pragma unroll
  for (int k = 0; k < 4; ++k) dst[k] = src[k];
}

// ---------------- sampler over bricked fp16 image, slab-predicated ----------
__device__ __forceinline__ float fetch_brick(const __half* __restrict__ bimg,
                                             int xi, int yi, int zi) {
  int lid = ((xi >> 1) * YB + (yi >> 2)) * ZB + (zi >> 2);
  int off = ((xi & 1) << 4) | ((yi & 3) << 2) | (zi & 3);
  return __half2float(bimg[lid * 32 + off]);
}

__global__ __launch_bounds__(256) void vm_sample_slab_kernel(
    const __half* __restrict__ bimg, const float* __restrict__ phi,
    float* __restrict__ out, int pass) {
  int i = blockIdx.x * 256 + threadIdx.x;

  // Issue all three phi loads up front (bytes are fetched line-wise anyway);
  // compute only cx before the slab predicate to keep masked-lane VALU low.
  float p0 = __builtin_nontemporal_load(&phi[i]);
  float p1 = __builtin_nontemporal_load(&phi[i + NTOT]);
  float p2 = __builtin_nontemporal_load(&phi[i + 2 * NTOT]);

  float cx = (p0 * 2.0f - 1.0f + 1.0f) * 0.5f * (float)(DD - 1);
  cx = fminf(fmaxf(cx, 0.0f), (float)(DD - 1));
  float x0f = floorf(cx);
  int x0 = (int)x0f;
  if (x0 / SLABX != pass) return;  // not this slab's sample

  float cy = (p1 * 2.0f - 1.0f + 1.0f) * 0.5f * (float)(HH - 1);
  float cz = (p2 * 2.0f - 1.0f + 1.0f) * 0.5f * (float)(WW - 1);
  cy = fminf(fmaxf(cy, 0.0f), (float)(HH - 1));
  cz = fminf(fmaxf(cz, 0.0f), (float)(WW - 1));

  float y0f = floorf(cy), z0f = floorf(cz);
  float fx = cx - x0f, fy = cy - y0f, fz = cz - z0f;
  int y0 = (int)y0f, z0 = (int)z0f;
  int x1 = min(x0 + 1, DD - 1);
  int y1 = min(y0 + 1, HH - 1);
  int z1 = min(z0 + 1, WW - 1);

  float v000 = fetch_brick(bimg, x0, y0, z0);
  float v001 = fetch_brick(bimg, x0, y0, z1);
  float v010 = fetch_brick(bimg, x0, y1, z0);
  float v011 = fetch_brick(bimg, x0, y1, z1);
  float v100 = fetch_brick(bimg, x1, y0, z0);
  float v101 = fetch_brick(bimg, x1, y0, z1);
  float v110 = fetch_brick(bimg, x1, y1, z0);
  float v111 = fetch_brick(bimg, x1, y1, z1);

  float gx0 = 1.0f - fx, gy0 = 1.0f - fy, gz0 = 1.0f - fz;
  float c00 = v000 * gz0 + v001 * fz;
  float c01 = v010 * gz0 + v011 * fz;
  float c10 = v100 * gz0 + v101 * fz;
  float c11 = v110 * gz0 + v111 * fz;
  float c0 = c00 * gy0 + c01 * fy;
  float c1 = c10 * gy0 + c11 * fy;
  __builtin_nontemporal_store(c0 * gx0 + c1 * fx, &out[i]);
}

// ---------------- fallback (ws too small): direct fp32 gather ----------------
__global__ __launch_bounds__(256) void vm_direct_kernel(
    const float* __restrict__ img, const float* __restrict__ phi,
    float* __restrict__ out) {
  int i = blockIdx.x * 256 + threadIdx.x;
  if (i >= NTOT) return;
  float p0 = phi[i], p1 = phi[i + NTOT], p2 = phi[i + 2 * NTOT];
  float cx = (p0 * 2.0f - 1.0f + 1.0f) * 0.5f * (float)(DD - 1);
  float cy = (p1 * 2.0f - 1.0f + 1.0f) * 0.5f * (float)(HH - 1);
  float cz = (p2 * 2.0f - 1.0f + 1.0f) * 0.5f * (float)(WW - 1);
  cx = fminf(fmaxf(cx, 0.0f), (float)(DD - 1));
  cy = fminf(fmaxf(cy, 0.0f), (float)(HH - 1));
  cz = fminf(fmaxf(cz, 0.0f), (float)(WW - 1));
  float x0f = floorf(cx), y0f = floorf(cy), z0f = floorf(cz);
  float fx = cx - x0f, fy = cy - y0f, fz = cz - z0f;
  int x0 = (int)x0f, y0 = (int)y0f, z0 = (int)z0f;
  int x1 = min(x0 + 1, DD - 1), y1 = min(y0 + 1, HH - 1), z1 = min(z0 + 1, WW - 1);
  int b00 = (x0 * HH + y0) * WW, b01 = (x0 * HH + y1) * WW;
  int b10 = (x1 * HH + y0) * WW, b11 = (x1 * HH + y1) * WW;
  float v000 = img[b00 + z0], v001 = img[b00 + z1];
  float v010 = img[b01 + z0], v011 = img[b01 + z1];
  float v100 = img[b10 + z0], v101 = img[b10 + z1];
  float v110 = img[b11 + z0], v111 = img[b11 + z1];
  float gx0 = 1.0f - fx, gy0 = 1.0f - fy, gz0 = 1.0f - fz;
  float c00 = v000 * gz0 + v001 * fz, c01 = v010 * gz0 + v011 * fz;
  float c10 = v100 * gz0 + v101 * fz, c11 = v110 * gz0 + v111 * fz;
  float c0 = c00 * gy0 + c01 * fy, c1 = c10 * gy0 + c11 * fy;
  out[i] = c0 * gx0 + c1 * fx;
}

extern "C" void kernel_launch(void* const* d_in, const int* in_sizes, int n_in,
                              void* d_out, int out_size, void* d_ws, size_t ws_size,
                              hipStream_t stream) {
  const float* img = (const float*)d_in[0];
  const float* phi = (const float*)d_in[1];
  float* out = (float*)d_out;

  const size_t need = (size_t)NLINES * 64;  // 13.76 MB fp16 brick image
  if (ws_size >= need) {
    __half2* bimg2 = (__half2*)d_ws;
    vm_repack_kernel<<<NLINES / 256, 256, 0, stream>>>(img, bimg2);
    const __half* bimg = (const __half*)d_ws;
    // 4 slab passes; kernel-boundary barriers give clean temporal phases so
    // each pass's 3.6 MB slab stays resident in every XCD's 4 MB L2.
    for (int pass = 0; pass < NPASS; ++pass) {
      vm_sample_slab_kernel<<<NTOT / 256, 256, 0, stream>>>(bimg, phi, out, pass);
    }
  } else {
    vm_direct_kernel<<<NTOT / 256, 256, 0, stream>>>(img, phi, out);
  }
}